// Round 1
// baseline (51.363 us; speedup 1.0000x reference)
//
#include <hip/hip_runtime.h>
#include <cfloat>
#include <cmath>

#define B_    32
#define C_    2048
#define NTILES (B_ * C_)
#define NREG  14

// region r -> row range [c_rs, c_re), column-range index c_ci
// col-range order in LDS: 0=A[0,21) 1=B[11,32) 2=C[0,16) 3=D[8,24) 4=E[16,32) 5=F[0,32)
__constant__ int c_rs[NREG] = {0, 0, 0,11,11, 0, 0, 0, 8, 8, 8,16,16,16};
__constant__ int c_re[NREG] = {32,21,21,32,32,16,16,16,24,24,24,32,32,32};
__constant__ int c_ci[NREG] = {5, 0, 1, 0, 1, 2, 3, 4, 2, 3, 4, 2, 3, 4};

__global__ __launch_bounds__(256) void rmac_phase1(const float* __restrict__ x,
                                                   float* __restrict__ m) {
    __shared__ float lds[4][64][6];
    const int tid  = threadIdx.x;
    const int wv   = tid >> 6;      // wave 0..3
    const int l    = tid & 63;      // lane
    const int half = l >> 5;        // which of the wave's 2 tiles
    const int row  = l & 31;        // row within tile
    const long tile = (long)blockIdx.x * 8 + wv * 2 + half;
    const float4* p = (const float4*)(x + tile * 1024 + row * 32);

    float4 v0 = p[0]; float4 v1 = p[1]; float4 v2 = p[2]; float4 v3 = p[3];
    float4 v4 = p[4]; float4 v5 = p[5]; float4 v6 = p[6]; float4 v7 = p[7];

    // disjoint column segments: [0,8) [8,11) [11,16) [16,21) [21,24) [24,32)
    float s0 = fmaxf(fmaxf(fmaxf(v0.x,v0.y),fmaxf(v0.z,v0.w)),
                     fmaxf(fmaxf(v1.x,v1.y),fmaxf(v1.z,v1.w)));           // 0-7
    float s1 = fmaxf(v2.x, fmaxf(v2.y, v2.z));                            // 8-10
    float s2 = fmaxf(fmaxf(v2.w, v3.x), fmaxf(fmaxf(v3.y,v3.z), v3.w));   // 11-15
    float s3 = fmaxf(fmaxf(v4.x, v4.y), fmaxf(fmaxf(v4.z,v4.w), v5.x));   // 16-20
    float s4 = fmaxf(v5.y, fmaxf(v5.z, v5.w));                            // 21-23
    float s5 = fmaxf(fmaxf(fmaxf(v6.x,v6.y),fmaxf(v6.z,v6.w)),
                     fmaxf(fmaxf(v7.x,v7.y),fmaxf(v7.z,v7.w)));           // 24-31

    float A  = fmaxf(fmaxf(s0,s1), fmaxf(s2,s3));   // cols [0,21)
    float Bv = fmaxf(fmaxf(s2,s3), fmaxf(s4,s5));   // cols [11,32)
    float Cv = fmaxf(fmaxf(s0,s1), s2);             // cols [0,16)
    float Dv = fmaxf(fmaxf(s1,s2), fmaxf(s3,s4));   // cols [8,24)
    float E  = fmaxf(s3, fmaxf(s4,s5));             // cols [16,32)
    float F  = fmaxf(A, fmaxf(s4,s5));              // cols [0,32)

    lds[wv][l][0]=A;  lds[wv][l][1]=Bv; lds[wv][l][2]=Cv;
    lds[wv][l][3]=Dv; lds[wv][l][4]=E;  lds[wv][l][5]=F;
    __syncthreads();

    const int reg = (l < NREG) ? l : ((l >= 32 && l < 32 + NREG) ? (l - 32) : -1);
    if (reg >= 0) {
        const int h = l >> 5;
        const int a = c_rs[reg], b = c_re[reg], c = c_ci[reg];
        float acc = -FLT_MAX;
        #pragma unroll
        for (int i = 0; i < 32; ++i) {
            float v = lds[wv][h * 32 + i][c];
            acc = (i >= a && i < b) ? fmaxf(acc, v) : acc;
        }
        const long t2 = (long)blockIdx.x * 8 + wv * 2 + h;
        m[t2 * 16 + reg] = acc;
    }
}

__global__ __launch_bounds__(256) void rmac_phase2(const float* __restrict__ m,
                                                   float* __restrict__ out) {
    const int b = blockIdx.x;
    const int t = threadIdx.x;
    __shared__ float sred[4][NREG];
    __shared__ float sinv[NREG];

    float acc[NREG];
    #pragma unroll
    for (int r = 0; r < NREG; ++r) acc[r] = 0.f;

    #pragma unroll
    for (int k = 0; k < 8; ++k) {
        const int ch = t + k * 256;
        const float* q = m + ((long)b * C_ + ch) * 16;
        #pragma unroll
        for (int r = 0; r < NREG; ++r) { float v = q[r]; acc[r] += v * v; }
    }

    #pragma unroll
    for (int r = 0; r < NREG; ++r) {
        #pragma unroll
        for (int off = 32; off >= 1; off >>= 1)
            acc[r] += __shfl_xor(acc[r], off, 64);
    }
    const int wv = t >> 6, ln = t & 63;
    if (ln == 0) {
        #pragma unroll
        for (int r = 0; r < NREG; ++r) sred[wv][r] = acc[r];
    }
    __syncthreads();
    if (t < NREG) {
        float s = sred[0][t] + sred[1][t] + sred[2][t] + sred[3][t];
        float w = (t == 0) ? 2.f : 1.f;       // full region appears twice in the sum
        sinv[t] = w / (sqrtf(s) + 1e-6f);
    }
    __syncthreads();

    #pragma unroll
    for (int k = 0; k < 8; ++k) {
        const int ch = t + k * 256;
        const float* q = m + ((long)b * C_ + ch) * 16;
        float o = 0.f;
        #pragma unroll
        for (int r = 0; r < NREG; ++r) o += q[r] * sinv[r];
        out[(long)b * C_ + ch] = o;
    }
}

extern "C" void kernel_launch(void* const* d_in, const int* in_sizes, int n_in,
                              void* d_out, int out_size, void* d_ws, size_t ws_size,
                              hipStream_t stream) {
    const float* x = (const float*)d_in[0];
    float* m   = (float*)d_ws;        // NTILES * 16 floats = 4 MiB scratch
    float* out = (float*)d_out;
    rmac_phase1<<<NTILES / 8, 256, 0, stream>>>(x, m);
    rmac_phase2<<<B_, 256, 0, stream>>>(m, out);
}

// Round 2
// 48.685 us; speedup vs baseline: 1.0550x; 1.0550x over previous
//
#include <hip/hip_runtime.h>
#include <cfloat>
#include <cmath>

#define B_    32
#define C_    2048
#define NTILES (B_ * C_)
#define NREG  14

// region r -> row range [c_rs, c_re), column-range index c_ci
// col-range order: 0=A[0,21) 1=B[11,32) 2=C[0,16) 3=D[8,24) 4=E[16,32) 5=F[0,32)
__constant__ int c_rs[NREG] = {0, 0, 0,11,11, 0, 0, 0, 8, 8, 8,16,16,16};
__constant__ int c_re[NREG] = {32,21,21,32,32,16,16,16,24,24,24,32,32,32};
__constant__ int c_ci[NREG] = {5, 0, 1, 0, 1, 2, 3, 4, 2, 3, 4, 2, 3, 4};

// Phase 1: 8 tiles (= 8 channels of one batch) per block.
// Writes m[tile][r] and per-block partial sums-of-squares partials[block][r].
__global__ __launch_bounds__(256) void rmac_phase1(const float* __restrict__ x,
                                                   float* __restrict__ m,
                                                   float* __restrict__ partials) {
    __shared__ float lds[4][64][6];
    __shared__ float sq[4][2][NREG];
    const int tid  = threadIdx.x;
    const int wv   = tid >> 6;      // wave 0..3
    const int l    = tid & 63;      // lane
    const int half = l >> 5;        // which of the wave's 2 tiles
    const int row  = l & 31;        // row within tile
    const long tile = (long)blockIdx.x * 8 + wv * 2 + half;
    const float4* p = (const float4*)(x + tile * 1024 + row * 32);

    float4 v0 = p[0]; float4 v1 = p[1]; float4 v2 = p[2]; float4 v3 = p[3];
    float4 v4 = p[4]; float4 v5 = p[5]; float4 v6 = p[6]; float4 v7 = p[7];

    // disjoint column segments: [0,8) [8,11) [11,16) [16,21) [21,24) [24,32)
    float s0 = fmaxf(fmaxf(fmaxf(v0.x,v0.y),fmaxf(v0.z,v0.w)),
                     fmaxf(fmaxf(v1.x,v1.y),fmaxf(v1.z,v1.w)));           // 0-7
    float s1 = fmaxf(v2.x, fmaxf(v2.y, v2.z));                            // 8-10
    float s2 = fmaxf(fmaxf(v2.w, v3.x), fmaxf(fmaxf(v3.y,v3.z), v3.w));   // 11-15
    float s3 = fmaxf(fmaxf(v4.x, v4.y), fmaxf(fmaxf(v4.z,v4.w), v5.x));   // 16-20
    float s4 = fmaxf(v5.y, fmaxf(v5.z, v5.w));                            // 21-23
    float s5 = fmaxf(fmaxf(fmaxf(v6.x,v6.y),fmaxf(v6.z,v6.w)),
                     fmaxf(fmaxf(v7.x,v7.y),fmaxf(v7.z,v7.w)));           // 24-31

    float A  = fmaxf(fmaxf(s0,s1), fmaxf(s2,s3));   // cols [0,21)
    float Bv = fmaxf(fmaxf(s2,s3), fmaxf(s4,s5));   // cols [11,32)
    float Cv = fmaxf(fmaxf(s0,s1), s2);             // cols [0,16)
    float Dv = fmaxf(fmaxf(s1,s2), fmaxf(s3,s4));   // cols [8,24)
    float E  = fmaxf(s3, fmaxf(s4,s5));             // cols [16,32)
    float F  = fmaxf(A, fmaxf(s4,s5));              // cols [0,32)

    lds[wv][l][0]=A;  lds[wv][l][1]=Bv; lds[wv][l][2]=Cv;
    lds[wv][l][3]=Dv; lds[wv][l][4]=E;  lds[wv][l][5]=F;
    __syncthreads();

    const int reg = (l < NREG) ? l : ((l >= 32 && l < 32 + NREG) ? (l - 32) : -1);
    if (reg >= 0) {
        const int h = l >> 5;
        const int a = c_rs[reg], b = c_re[reg], c = c_ci[reg];
        float acc = -FLT_MAX;
        #pragma unroll
        for (int i = 0; i < 32; ++i) {
            float v = lds[wv][h * 32 + i][c];
            acc = (i >= a && i < b) ? fmaxf(acc, v) : acc;
        }
        const long t2 = (long)blockIdx.x * 8 + wv * 2 + h;
        m[t2 * 16 + reg] = acc;
        sq[wv][h][reg] = acc * acc;
    }
    __syncthreads();
    if (tid < NREG) {
        float s = 0.f;
        #pragma unroll
        for (int w = 0; w < 4; ++w)
            #pragma unroll
            for (int h2 = 0; h2 < 2; ++h2) s += sq[w][h2][tid];
        partials[(long)blockIdx.x * 16 + tid] = s;
    }
}

// Phase 2: 256 blocks (8 per batch). Each block redundantly reduces its
// batch's 256 block-partials (L2-hot, 16KB) -> inv norms, then applies.
__global__ __launch_bounds__(256) void rmac_phase2(const float* __restrict__ m,
                                                   const float* __restrict__ partials,
                                                   float* __restrict__ out) {
    const int t = threadIdx.x;
    const int b = blockIdx.x >> 3;                    // 8 blocks per batch
    const float4* pp = (const float4*)(partials + ((long)(b * 256 + t)) * 16);
    float4 p0 = pp[0], p1 = pp[1], p2 = pp[2], p3 = pp[3];
    float v[NREG] = {p0.x,p0.y,p0.z,p0.w, p1.x,p1.y,p1.z,p1.w,
                     p2.x,p2.y,p2.z,p2.w, p3.x,p3.y};
    #pragma unroll
    for (int r = 0; r < NREG; ++r) {
        #pragma unroll
        for (int off = 32; off >= 1; off >>= 1)
            v[r] += __shfl_xor(v[r], off, 64);
    }
    __shared__ float sred[4][NREG];
    __shared__ float sinv[NREG];
    if ((t & 63) == 0) {
        #pragma unroll
        for (int r = 0; r < NREG; ++r) sred[t >> 6][r] = v[r];
    }
    __syncthreads();
    if (t < NREG) {
        float s = sred[0][t] + sred[1][t] + sred[2][t] + sred[3][t];
        float w = (t == 0) ? 2.f : 1.f;   // full region appears twice in the sum
        sinv[t] = w / (sqrtf(s) + 1e-6f);
    }
    __syncthreads();

    const long g = (long)blockIdx.x * 256 + t;        // one channel per thread
    const float4* q = (const float4*)(m + g * 16);
    float4 a0 = q[0], a1 = q[1], a2 = q[2], a3 = q[3];
    float o = a0.x*sinv[0] + a0.y*sinv[1] + a0.z*sinv[2]  + a0.w*sinv[3]
            + a1.x*sinv[4] + a1.y*sinv[5] + a1.z*sinv[6]  + a1.w*sinv[7]
            + a2.x*sinv[8] + a2.y*sinv[9] + a2.z*sinv[10] + a2.w*sinv[11]
            + a3.x*sinv[12] + a3.y*sinv[13];
    out[g] = o;
}

extern "C" void kernel_launch(void* const* d_in, const int* in_sizes, int n_in,
                              void* d_out, int out_size, void* d_ws, size_t ws_size,
                              hipStream_t stream) {
    const float* x = (const float*)d_in[0];
    float* m        = (float*)d_ws;                   // 64K tiles * 16 f = 4 MiB
    float* partials = m + (long)NTILES * 16;          // 8192 blocks * 16 f = 512 KiB
    float* out      = (float*)d_out;
    rmac_phase1<<<NTILES / 8, 256, 0, stream>>>(x, m, partials);
    rmac_phase2<<<256, 256, 0, stream>>>(m, partials, out);
}

// Round 3
// 47.808 us; speedup vs baseline: 1.0744x; 1.0183x over previous
//
#include <hip/hip_runtime.h>
#include <cfloat>
#include <cmath>

#define B_    32
#define C_    2048
#define NTILES (B_ * C_)
#define NREG  14

// region r -> row range [c_rs, c_re), column-range index c_ci
// col-range order: 0=A[0,21) 1=B[11,32) 2=C[0,16) 3=D[8,24) 4=E[16,32) 5=F[0,32)
__constant__ int c_rs[NREG] = {0, 0, 0,11,11, 0, 0, 0, 8, 8, 8,16,16,16};
__constant__ int c_re[NREG] = {32,21,21,32,32,16,16,16,24,24,24,32,32,32};
__constant__ int c_ci[NREG] = {5, 0, 1, 0, 1, 2, 3, 4, 2, 3, 4, 2, 3, 4};

// Phase 1: 8 tiles (= 8 channels of one batch) per block.
// Writes m[tile][r] and per-block partial sums-of-squares partials[block][r].
__global__ __launch_bounds__(256) void rmac_phase1(const float* __restrict__ x,
                                                   float* __restrict__ m,
                                                   float* __restrict__ partials) {
    __shared__ float lds[4][64][6];
    __shared__ float sq[4][2][NREG];
    const int tid  = threadIdx.x;
    const int wv   = tid >> 6;      // wave 0..3
    const int l    = tid & 63;      // lane
    const int half = l >> 5;        // which of the wave's 2 tiles
    const int row  = l & 31;        // row within tile
    const long tile = (long)blockIdx.x * 8 + wv * 2 + half;
    const float4* p = (const float4*)(x + tile * 1024 + row * 32);

    float4 v0 = p[0]; float4 v1 = p[1]; float4 v2 = p[2]; float4 v3 = p[3];
    float4 v4 = p[4]; float4 v5 = p[5]; float4 v6 = p[6]; float4 v7 = p[7];

    // disjoint column segments: [0,8) [8,11) [11,16) [16,21) [21,24) [24,32)
    float s0 = fmaxf(fmaxf(fmaxf(v0.x,v0.y),fmaxf(v0.z,v0.w)),
                     fmaxf(fmaxf(v1.x,v1.y),fmaxf(v1.z,v1.w)));           // 0-7
    float s1 = fmaxf(v2.x, fmaxf(v2.y, v2.z));                            // 8-10
    float s2 = fmaxf(fmaxf(v2.w, v3.x), fmaxf(fmaxf(v3.y,v3.z), v3.w));   // 11-15
    float s3 = fmaxf(fmaxf(v4.x, v4.y), fmaxf(fmaxf(v4.z,v4.w), v5.x));   // 16-20
    float s4 = fmaxf(v5.y, fmaxf(v5.z, v5.w));                            // 21-23
    float s5 = fmaxf(fmaxf(fmaxf(v6.x,v6.y),fmaxf(v6.z,v6.w)),
                     fmaxf(fmaxf(v7.x,v7.y),fmaxf(v7.z,v7.w)));           // 24-31

    float A  = fmaxf(fmaxf(s0,s1), fmaxf(s2,s3));   // cols [0,21)
    float Bv = fmaxf(fmaxf(s2,s3), fmaxf(s4,s5));   // cols [11,32)
    float Cv = fmaxf(fmaxf(s0,s1), s2);             // cols [0,16)
    float Dv = fmaxf(fmaxf(s1,s2), fmaxf(s3,s4));   // cols [8,24)
    float E  = fmaxf(s3, fmaxf(s4,s5));             // cols [16,32)
    float F  = fmaxf(A, fmaxf(s4,s5));              // cols [0,32)

    lds[wv][l][0]=A;  lds[wv][l][1]=Bv; lds[wv][l][2]=Cv;
    lds[wv][l][3]=Dv; lds[wv][l][4]=E;  lds[wv][l][5]=F;
    __syncthreads();

    const int reg = (l < NREG) ? l : ((l >= 32 && l < 32 + NREG) ? (l - 32) : -1);
    if (reg >= 0) {
        const int h = l >> 5;
        const int a = c_rs[reg], b = c_re[reg], c = c_ci[reg];
        float acc = -FLT_MAX;
        #pragma unroll
        for (int i = 0; i < 32; ++i) {
            float v = lds[wv][h * 32 + i][c];
            acc = (i >= a && i < b) ? fmaxf(acc, v) : acc;
        }
        const long t2 = (long)blockIdx.x * 8 + wv * 2 + h;
        m[t2 * 16 + reg] = acc;
        sq[wv][h][reg] = acc * acc;
    }
    __syncthreads();
    if (tid < NREG) {
        float s = 0.f;
        #pragma unroll
        for (int w = 0; w < 4; ++w)
            #pragma unroll
            for (int h2 = 0; h2 < 2; ++h2) s += sq[w][h2][tid];
        partials[(long)blockIdx.x * 16 + tid] = s;
    }
}

// Phase 2: 256 blocks (8 per batch). m-loads issued at entry (overlap the
// partials reduce). Partials reduce is transposed: thread t owns component
// t&15, sums 16 rows with coalesced loads, then 2 shfl_xor + tiny LDS.
__global__ __launch_bounds__(256) void rmac_phase2(const float* __restrict__ m,
                                                   const float* __restrict__ partials,
                                                   float* __restrict__ out) {
    const int t = threadIdx.x;
    const int b = blockIdx.x >> 3;                    // 8 blocks per batch

    // Issue the m loads for this thread's channel immediately (independent).
    const long g = (long)blockIdx.x * 256 + t;        // one channel per thread
    const float4* q = (const float4*)(m + g * 16);
    float4 a0 = q[0], a1 = q[1], a2 = q[2], a3 = q[3];

    // Transposed partial reduction: comp = t&15, rows (t>>4) + 16k, k=0..15.
    const int comp = t & 15;
    const int r0   = t >> 4;
    const float* pbase = partials + (long)b * 256 * 16;
    float acc = 0.f;
    #pragma unroll
    for (int k = 0; k < 16; ++k)
        acc += pbase[(r0 + k * 16) * 16 + comp];      // 256B/wave, coalesced
    acc += __shfl_xor(acc, 16, 64);
    acc += __shfl_xor(acc, 32, 64);

    __shared__ float sred[4][16];
    __shared__ float sinv[16];
    if ((t & 63) < 16) sred[t >> 6][comp] = acc;
    __syncthreads();
    if (t < NREG) {
        float s = sred[0][t] + sred[1][t] + sred[2][t] + sred[3][t];
        float w = (t == 0) ? 2.f : 1.f;   // full region appears twice in the sum
        sinv[t] = w / (sqrtf(s) + 1e-6f);
    }
    __syncthreads();

    float o = a0.x*sinv[0] + a0.y*sinv[1] + a0.z*sinv[2]  + a0.w*sinv[3]
            + a1.x*sinv[4] + a1.y*sinv[5] + a1.z*sinv[6]  + a1.w*sinv[7]
            + a2.x*sinv[8] + a2.y*sinv[9] + a2.z*sinv[10] + a2.w*sinv[11]
            + a3.x*sinv[12] + a3.y*sinv[13];
    out[g] = o;
}

extern "C" void kernel_launch(void* const* d_in, const int* in_sizes, int n_in,
                              void* d_out, int out_size, void* d_ws, size_t ws_size,
                              hipStream_t stream) {
    const float* x = (const float*)d_in[0];
    float* m        = (float*)d_ws;                   // 64K tiles * 16 f = 4 MiB
    float* partials = m + (long)NTILES * 16;          // 8192 blocks * 16 f = 512 KiB
    float* out      = (float*)d_out;
    rmac_phase1<<<NTILES / 8, 256, 0, stream>>>(x, m, partials);
    rmac_phase2<<<256, 256, 0, stream>>>(m, partials, out);
}